// Round 1
// 1928.766 us; speedup vs baseline: 1.4622x; 1.4622x over previous
//
#include <hip/hip_runtime.h>

// SCRN 2-layer + fc head — LAYER-PIPELINED PERSISTENT MEGA-KERNEL round.
// Prior best (2820 us): scan1 (1306) -> gemm/ema/gemm -> scan2 (1306), fully serialized.
// Each scan is latency-bound on the per-step inter-block exchange (2.55 us/step; MfmaUtil
// 0.5%, HBM 1.8% -> no roofline in sight). Layer-2 depends on layer-1 only pointwise in t,
// and the EMA commutes with the linear maps:
//     d2_t = 0.05 d2_{t-1} + 0.95 (h1_t @ W2^T + b2),  W2 = Uc1@Wx1,  b2 = Uc1@bx1.
// So run all of it concurrently in ONE 24-block kernel:
//   blocks 0-7  : scan1 (proven loop; publishes tagged h1_t into a 256-slot ring; hs1 dropped)
//   blocks 8-15 : e-blocks (ingest h1_t, e=h1_t@W2^T same MFMA geometry, f32-register EMA,
//                 publish tagged d2_t into 128-slot ring; backpressured by scan2 progress)
//   blocks 16-23: scan2 (proven loop; d2_t ingested from the e-ring via tagged polls)
// Layer-1 front (xp1 gemm -> ema -> d1 gemm) is byte-identical to the proven path.
// All tagged buffers are zeroed per launch (also fixes the latent stale-tag hazard).
// ws layout (84 MiB exactly): ctrl+weights 0..4M | ring 4..36M (overlays x16,xp1) |
// d2ring 36..52M (overlays cb1) | d1 52..84M.

typedef _Float16 f16;
typedef _Float16 f16x8 __attribute__((ext_vector_type(8)));
typedef _Float16 f16x2 __attribute__((ext_vector_type(2)));
typedef float f32x4 __attribute__((ext_vector_type(4)));
typedef unsigned short u16;
typedef unsigned int u32;
typedef unsigned short u16x8 __attribute__((ext_vector_type(8)));
typedef unsigned long long u64;

#define DEV __device__ __forceinline__

constexpr int Tt = 512, HIDq = 512;

DEV float bf2f(u16 u) { unsigned v = ((unsigned)u) << 16; float f; __builtin_memcpy(&f, &v, 4); return f; }
DEV u16 f2bf(float f) { unsigned u; __builtin_memcpy(&u, &f, 4); u = (u + 0x7fffu + ((u >> 16) & 1u)) >> 16; return (u16)u; }
DEV float fast_tanh(float x) {
  x = fminf(30.f, fmaxf(-30.f, x));
  float e = exp2f(x * 2.885390081777927f);   // e^(2x)
  return (e - 1.f) / (e + 1.f);
}
DEV u64 al64(const u64* p) { return __hip_atomic_load(p, __ATOMIC_RELAXED, __HIP_MEMORY_SCOPE_AGENT); }
DEV u32 al32(const u32* p) { return __hip_atomic_load(p, __ATOMIC_RELAXED, __HIP_MEMORY_SCOPE_AGENT); }
DEV void as32(u32* p, u32 v) { __hip_atomic_store(p, v, __ATOMIC_RELAXED, __HIP_MEMORY_SCOPE_AGENT); }

// ---- dtype probe: Wx0 entries bounded by 1/16; bf16 decode of f32 mantissa halves -> huge ----
__global__ void k_probe(const u16* __restrict__ w, int* __restrict__ dmode) {
  __shared__ int s;
  if (threadIdx.x == 0) s = 0;
  __syncthreads();
  int found = 0;
  for (int i = threadIdx.x; i < 8192; i += 256) {
    float v = bf2f(w[i]);
    if (fabsf(v) > 0.5f) found = 1;
  }
  if (found) atomicOr(&s, 1);
  __syncthreads();
  if (threadIdx.x == 0) *dmode = s;   // 0 = bf16 buffers, 1 = f32 buffers
}

// ---- convert n8*8 elements (bf16 or f32 per mode) -> fp16 ----
__global__ void k_cvt(const void* __restrict__ src, f16* __restrict__ dst, int n8,
                      const int* __restrict__ dmode) {
  int i = blockIdx.x * 256 + threadIdx.x;
  if (i >= n8) return;
  f16x8 o;
  if (*dmode) {
    const float4* s = (const float4*)src;
    float4 a = s[2*i], b = s[2*i+1];
    o[0]=(f16)a.x; o[1]=(f16)a.y; o[2]=(f16)a.z; o[3]=(f16)a.w;
    o[4]=(f16)b.x; o[5]=(f16)b.y; o[6]=(f16)b.z; o[7]=(f16)b.w;
  } else {
    u16x8 v = ((const u16x8*)src)[i];
#pragma unroll
    for (int j = 0; j < 8; ++j) o[j] = (f16)bf2f(v[j]);
  }
  ((f16x8*)dst)[i] = o;
}

__global__ void k_zero(u16* __restrict__ out) {  // diagnostic fallback (ws too small)
  out[blockIdx.x * 256 + threadIdx.x] = 0;
}

// ---- transpose [R][2^cshift] -> [2^cshift][R] (small weights only) ----
__global__ __launch_bounds__(256) void k_tr(const f16* __restrict__ src, f16* __restrict__ dst,
                                            int R, int cshift) {
  int idx = blockIdx.x * 256 + threadIdx.x;
  int r = idx >> cshift, c = idx & ((1 << cshift) - 1);
  dst[c * R + r] = src[idx];
}

// ---- b2[j] = sum_c Uc1[j,c] * bx1[c] ----
__global__ __launch_bounds__(512) void k_bias(const f16* __restrict__ Uc, const f16* __restrict__ bx,
                                              f16* __restrict__ out) {
  int j = threadIdx.x;
  float a = 0.f;
  for (int c = 0; c < 256; ++c) a += (float)Uc[j * 256 + c] * (float)bx[c];
  out[j] = (f16)a;
}

// ---- EMA c_t = 0.05 c_{t-1} + 0.95 xp_t ; 16-step warmup per 64-chunk (batch-major) ----
__global__ __launch_bounds__(128) void k_ema(const f16* __restrict__ xp, f16* __restrict__ c) {
  int b = blockIdx.x >> 3, chunk = blockIdx.x & 7;
  int t0 = chunk * 64;
  int ch = threadIdx.x;
  const f16x2* src = (const f16x2*)(xp + (size_t)b * Tt * 256) + ch;
  f16x2* dst = (f16x2*)(c + (size_t)b * Tt * 256) + ch;
  float c0 = 0.f, c1 = 0.f;
  int ts = (t0 >= 16) ? t0 - 16 : 0;
  for (int tt = ts; tt < t0 + 64; ++tt) {
    f16x2 v = src[(size_t)tt * 128];
    c0 = 0.05f * c0 + 0.95f * (float)v.x;
    c1 = 0.05f * c1 + 0.95f * (float)v.y;
    if (tt >= t0) { f16x2 o; o.x = (f16)c0; o.y = (f16)c1; dst[(size_t)tt * 128] = o; }
  }
}

// ---- GEMM: C = A[M,K] @ B[N,K]^T (+bias). TD: store C time-major (row b*512+t -> t*64+b) ----
template<bool HAS_BIAS, bool TD>
__global__ __launch_bounds__(256) void k_gemm(const f16* __restrict__ A, const f16* __restrict__ Bm,
                                              const f16* __restrict__ bias, f16* __restrict__ C,
                                              int M, int N, int K) {
  __shared__ f16 As[128][40];
  __shared__ f16 Bs[128][40];
  const int tid = threadIdx.x, lane = tid & 63, wv = tid >> 6;
  const int l15 = lane & 15, q = lane >> 4;
  const int wm = wv >> 1, wn = wv & 1;
  const int m0 = blockIdx.y * 128, n0 = blockIdx.x * 128;
  const int srow = tid >> 1, sseg = tid & 1;
  f32x4 acc[4][4] = {};
  const f16* ga = A  + (size_t)(m0 + srow) * K + sseg * 16;
  const f16* gb = Bm + (size_t)(n0 + srow) * K + sseg * 16;
  for (int k0 = 0; k0 < K; k0 += 32) {
    f16x8 a0 = *(const f16x8*)(ga + k0);
    f16x8 a1 = *(const f16x8*)(ga + k0 + 8);
    f16x8 b0 = *(const f16x8*)(gb + k0);
    f16x8 b1 = *(const f16x8*)(gb + k0 + 8);
    __syncthreads();
    *(f16x8*)&As[srow][sseg*16]     = a0;
    *(f16x8*)&As[srow][sseg*16 + 8] = a1;
    *(f16x8*)&Bs[srow][sseg*16]     = b0;
    *(f16x8*)&Bs[srow][sseg*16 + 8] = b1;
    __syncthreads();
    f16x8 af[4], bf[4];
#pragma unroll
    for (int i = 0; i < 4; ++i) af[i] = *(const f16x8*)&As[wm*64 + i*16 + l15][q*8];
#pragma unroll
    for (int i = 0; i < 4; ++i) bf[i] = *(const f16x8*)&Bs[wn*64 + i*16 + l15][q*8];
#pragma unroll
    for (int i = 0; i < 4; ++i)
#pragma unroll
      for (int j = 0; j < 4; ++j)
        acc[i][j] = __builtin_amdgcn_mfma_f32_16x16x32_f16(af[i], bf[j], acc[i][j], 0, 0, 0);
  }
#pragma unroll
  for (int j = 0; j < 4; ++j) {
    int col = n0 + wn*64 + j*16 + l15;
    float bv = HAS_BIAS ? (float)bias[col] : 0.f;
#pragma unroll
    for (int i = 0; i < 4; ++i)
#pragma unroll
      for (int r = 0; r < 4; ++r) {
        int row = m0 + wm*64 + i*16 + q*4 + r;
        size_t orow = TD ? (size_t)((row & 511) * 64 + (row >> 9)) : (size_t)row;
        C[orow * N + col] = (f16)(acc[i][j][r] + bv);
      }
  }
}

// ---- persistent mega-kernel: scan1 (0-7) | e-GEMM+EMA (8-15) | scan2 (16-23) ----
// ring : h1 tagged, 256 slots x [64][512] u32 (slot = t & 255, tag = t+1)
// d2r  : d2 tagged, 128 slots x [64][512] u32 (slot = t & 127, tag = t+1)
// hb2  : h2 tagged, 2 slots (identical to proven k_scan exchange)
// prog : 8 u32, scan2 block sb writes t after d2_t consumed (e-block backpressure)
__global__ __launch_bounds__(512, 2) void k_mega(const f16* __restrict__ Vh0,
                                                 const f16* __restrict__ Vh1,
                                                 const f16* __restrict__ W2,
                                                 const f16* __restrict__ b2,
                                                 const f16* __restrict__ d1,
                                                 u32* __restrict__ ring,
                                                 u32* __restrict__ d2r,
                                                 u32* __restrict__ hb2,
                                                 u32* __restrict__ prog) {
  __shared__ f16 hL[2][16][520];
  const int bb = blockIdx.x;
  const int tid = threadIdx.x, w = tid >> 6, lane = tid & 63;
  const int l15 = lane & 15, q = lane >> 4;

  if (bb < 8) {
    // ================= scan1: h1_t = tanh(d1_t + h1_{t-1} @ Vh0^T) -> ring ==============
    const int hf = bb & 1, g = bb >> 1;
    const int colbase = 256*hf + 32*w;
    f16x8 Bf[2][16];
#pragma unroll
    for (int j = 0; j < 2; ++j)
#pragma unroll
      for (int kk = 0; kk < 16; ++kk)
        Bf[j][kk] = *(const f16x8*)&Vh0[(size_t)(colbase + 16*j + l15) * HIDq + kk*32 + q*8];
    for (int i = tid; i < 1024; i += 512) {
      int r = i >> 6, c = (i & 63) * 8;
      f16x8 z = {};
      *(f16x8*)&hL[0][r][c] = z;
    }
    float dv[2][4];
#pragma unroll
    for (int j = 0; j < 2; ++j)
#pragma unroll
      for (int r = 0; r < 4; ++r)
        dv[j][r] = (float)d1[(size_t)(16*g + q*4 + r) * HIDq + colbase + 16*j + l15];
    __syncthreads();
    const int irow = tid >> 5, ic8 = (tid & 31) * 8;
    const int pcol = 256*(hf ^ 1) + ic8;

    for (int t = 0; t < Tt; ++t) {
      const int rb = t & 1, wb = rb ^ 1;
      u32* rslot = ring + (size_t)(t & 255) * 32768;
      f32x4 a00 = {}, a01 = {}, a10 = {}, a11 = {};
#pragma unroll
      for (int kk = 0; kk < 16; ++kk) {
        f16x8 a = *(const f16x8*)&hL[rb][l15][kk*32 + q*8];
        if (kk & 1) {
          a01 = __builtin_amdgcn_mfma_f32_16x16x32_f16(a, Bf[0][kk], a01, 0, 0, 0);
          a11 = __builtin_amdgcn_mfma_f32_16x16x32_f16(a, Bf[1][kk], a11, 0, 0, 0);
        } else {
          a00 = __builtin_amdgcn_mfma_f32_16x16x32_f16(a, Bf[0][kk], a00, 0, 0, 0);
          a10 = __builtin_amdgcn_mfma_f32_16x16x32_f16(a, Bf[1][kk], a10, 0, 0, 0);
        }
      }
      const u32 tagw = (u32)(t + 1) << 16;
      u16 hbits[2][4];
#pragma unroll
      for (int j = 0; j < 2; ++j) {
        f32x4 s = j ? (a10 + a11) : (a00 + a01);
#pragma unroll
        for (int r = 0; r < 4; ++r) {
          float z = s[r] + dv[j][r];
          union { f16 h; u16 u; } cv; cv.h = (f16)fast_tanh(z);
          hbits[j][r] = cv.u;
          as32(&rslot[(size_t)(16*g + q*4 + r) * HIDq + colbase + 16*j + l15],
               tagw | (u32)cv.u);
        }
      }
#pragma unroll
      for (int j = 0; j < 2; ++j)
#pragma unroll
        for (int r = 0; r < 4; ++r) {
          union { u16 u; f16 h; } cv; cv.u = hbits[j][r];
          hL[wb][q*4 + r][colbase + 16*j + l15] = cv.h;
        }
      if (t < Tt - 1) {
#pragma unroll
        for (int j = 0; j < 2; ++j)
#pragma unroll
          for (int r = 0; r < 4; ++r)
            dv[j][r] = (float)d1[((size_t)(t+1)*64 + 16*g + q*4 + r) * HIDq + colbase + 16*j + l15];
      }
      // peer slab ingest (combined load + combined revalidation)
      {
        const u64* pp = (const u64*)(rslot + (size_t)(16*g + irow) * HIDq) + (pcol >> 1);
        u64 v[4];
#pragma unroll
        for (int jj = 0; jj < 4; ++jj) v[jj] = al64(pp + jj);
        for (;;) {
          u32 bad = 0;
#pragma unroll
          for (int jj = 0; jj < 4; ++jj)
            bad |= ((u32)v[jj] ^ tagw) | ((u32)(v[jj] >> 32) ^ tagw);
          if ((bad & 0xFFFF0000u) == 0) break;
#pragma unroll
          for (int jj = 0; jj < 4; ++jj) v[jj] = al64(pp + jj);
        }
        union { u32 wd[4]; f16x8 vv; } fr;
#pragma unroll
        for (int jj = 0; jj < 4; ++jj)
          fr.wd[jj] = __builtin_amdgcn_perm((u32)(v[jj] >> 32), (u32)v[jj], 0x05040100u);
        *(f16x8*)&hL[wb][irow][pcol] = fr.vv;
      }
      __syncthreads();
    }

  } else if (bb < 16) {
    // ================= e-block: d2_t = 0.05 d2 + 0.95 (h1_t @ W2^T + b2) -> d2r ==========
    const int eb = bb - 8, hf = eb & 1, g = eb >> 1;
    const int colbase = 256*hf + 32*w;
    f16x8 Bf[2][16];
#pragma unroll
    for (int j = 0; j < 2; ++j)
#pragma unroll
      for (int kk = 0; kk < 16; ++kk)
        Bf[j][kk] = *(const f16x8*)&W2[(size_t)(colbase + 16*j + l15) * HIDq + kk*32 + q*8];
    float bv[2] = { (float)b2[colbase + l15], (float)b2[colbase + 16 + l15] };
    float ed[2][4] = {};
    const int irow = tid >> 5, icol = (tid & 31) * 16;   // 16 rows x 32 thr x 16 u32-cols

    for (int t = 0; t < Tt; ++t) {
      // backpressure: about to overwrite d2_{t-128}; partner must have consumed it
      if (t >= 129 && tid == 0)
        while ((int)al32(&prog[eb]) < t - 128) { }
      const u32 tagw = (u32)(t + 1) << 16;
      // ingest h1_t (full 512 cols for our 16 rows): 8 u64/thread, combined revalidation
      {
        const u64* pp = (const u64*)(ring + (size_t)(t & 255) * 32768
                          + (size_t)(16*g + irow) * HIDq) + (icol >> 1);
        u64 v[8];
#pragma unroll
        for (int jj = 0; jj < 8; ++jj) v[jj] = al64(pp + jj);
        for (;;) {
          u32 bad = 0;
#pragma unroll
          for (int jj = 0; jj < 8; ++jj)
            bad |= ((u32)v[jj] ^ tagw) | ((u32)(v[jj] >> 32) ^ tagw);
          if ((bad & 0xFFFF0000u) == 0) break;
#pragma unroll
          for (int jj = 0; jj < 8; ++jj) v[jj] = al64(pp + jj);
        }
        union { u32 wd[8]; f16x8 vv[2]; } fr;
#pragma unroll
        for (int jj = 0; jj < 8; ++jj)
          fr.wd[jj] = __builtin_amdgcn_perm((u32)(v[jj] >> 32), (u32)v[jj], 0x05040100u);
        *(f16x8*)&hL[t & 1][irow][icol]     = fr.vv[0];
        *(f16x8*)&hL[t & 1][irow][icol + 8] = fr.vv[1];
      }
      __syncthreads();   // hL[t&1] complete; also orders publish after tid0's gate
      f32x4 a00 = {}, a01 = {}, a10 = {}, a11 = {};
#pragma unroll
      for (int kk = 0; kk < 16; ++kk) {
        f16x8 a = *(const f16x8*)&hL[t & 1][l15][kk*32 + q*8];
        if (kk & 1) {
          a01 = __builtin_amdgcn_mfma_f32_16x16x32_f16(a, Bf[0][kk], a01, 0, 0, 0);
          a11 = __builtin_amdgcn_mfma_f32_16x16x32_f16(a, Bf[1][kk], a11, 0, 0, 0);
        } else {
          a00 = __builtin_amdgcn_mfma_f32_16x16x32_f16(a, Bf[0][kk], a00, 0, 0, 0);
          a10 = __builtin_amdgcn_mfma_f32_16x16x32_f16(a, Bf[1][kk], a10, 0, 0, 0);
        }
      }
      u32* dslot = d2r + (size_t)(t & 127) * 32768;
#pragma unroll
      for (int j = 0; j < 2; ++j) {
        f32x4 s = j ? (a10 + a11) : (a00 + a01);
#pragma unroll
        for (int r = 0; r < 4; ++r) {
          ed[j][r] = 0.05f * ed[j][r] + 0.95f * (s[r] + bv[j]);
          union { f16 h; u16 u; } cv; cv.h = (f16)ed[j][r];
          as32(&dslot[(size_t)(16*g + q*4 + r) * HIDq + colbase + 16*j + l15],
               tagw | (u32)cv.u);
        }
      }
      // no 2nd barrier needed: next iter writes hL[(t+1)&1]; the single barrier keeps
      // waves <=1 step apart, so hL[t&1] can't be overwritten while still being read.
    }

  } else {
    // ================= scan2: h2_t = tanh(d2_t + h2_{t-1} @ Vh1^T) -> hb2 ===============
    const int sb = bb - 16, hf = sb & 1, g = sb >> 1;
    const int colbase = 256*hf + 32*w;
    f16x8 Bf[2][16];
#pragma unroll
    for (int j = 0; j < 2; ++j)
#pragma unroll
      for (int kk = 0; kk < 16; ++kk)
        Bf[j][kk] = *(const f16x8*)&Vh1[(size_t)(colbase + 16*j + l15) * HIDq + kk*32 + q*8];
    for (int i = tid; i < 1024; i += 512) {
      int r = i >> 6, c = (i & 63) * 8;
      f16x8 z = {};
      *(f16x8*)&hL[0][r][c] = z;
    }
    // d2_0 tagged poll (tag 1, slot 0)
    float dv[2][4];
    {
      const u32 tag2 = 1u << 16;
      const u32* dp = d2r + (size_t)(16*g + q*4) * HIDq + colbase + l15;
      u32 vv[8];
      for (;;) {
#pragma unroll
        for (int i = 0; i < 8; ++i) vv[i] = al32(dp + (size_t)(i & 3) * HIDq + 16*(i >> 2));
        u32 bad = 0;
#pragma unroll
        for (int i = 0; i < 8; ++i) bad |= vv[i] ^ tag2;
        if ((bad & 0xFFFF0000u) == 0) break;
      }
#pragma unroll
      for (int j = 0; j < 2; ++j)
#pragma unroll
        for (int r = 0; r < 4; ++r) {
          union { u16 u; f16 h; } cv; cv.u = (u16)vv[j*4 + r];
          dv[j][r] = (float)cv.h;
        }
    }
    __syncthreads();
    const int irow = tid >> 5, ic8 = (tid & 31) * 8;
    const int pcol = 256*(hf ^ 1) + ic8;

    for (int t = 0; t < Tt; ++t) {
      const int rb = t & 1, wb = rb ^ 1, slot = t & 1;
      if (tid == 0 && t > 0) as32(&prog[sb], (u32)t);   // d2_t consumed last iter (post-barrier)
      f32x4 a00 = {}, a01 = {}, a10 = {}, a11 = {};
#pragma unroll
      for (int kk = 0; kk < 16; ++kk) {
        f16x8 a = *(const f16x8*)&hL[rb][l15][kk*32 + q*8];
        if (kk & 1) {
          a01 = __builtin_amdgcn_mfma_f32_16x16x32_f16(a, Bf[0][kk], a01, 0, 0, 0);
          a11 = __builtin_amdgcn_mfma_f32_16x16x32_f16(a, Bf[1][kk], a11, 0, 0, 0);
        } else {
          a00 = __builtin_amdgcn_mfma_f32_16x16x32_f16(a, Bf[0][kk], a00, 0, 0, 0);
          a10 = __builtin_amdgcn_mfma_f32_16x16x32_f16(a, Bf[1][kk], a10, 0, 0, 0);
        }
      }
      const u32 tagw = (u32)(t + 1) << 16;
      u16 hbits[2][4];
#pragma unroll
      for (int j = 0; j < 2; ++j) {
        f32x4 s = j ? (a10 + a11) : (a00 + a01);
#pragma unroll
        for (int r = 0; r < 4; ++r) {
          float z = s[r] + dv[j][r];
          union { f16 h; u16 u; } cv; cv.h = (f16)fast_tanh(z);
          hbits[j][r] = cv.u;
          as32(&hb2[(size_t)(slot*64 + 16*g + q*4 + r) * HIDq + colbase + 16*j + l15],
               tagw | (u32)cv.u);
        }
      }
#pragma unroll
      for (int j = 0; j < 2; ++j)
#pragma unroll
        for (int r = 0; r < 4; ++r) {
          union { u16 u; f16 h; } cv; cv.u = hbits[j][r];
          hL[wb][q*4 + r][colbase + 16*j + l15] = cv.h;
        }
      // d2_{t+1} tagged poll (overlaps peer wait)
      if (t < Tt - 1) {
        const u32 tag2 = (u32)(t + 2) << 16;
        const u32* dp = d2r + (size_t)((t + 1) & 127) * 32768
                      + (size_t)(16*g + q*4) * HIDq + colbase + l15;
        u32 vv[8];
        for (;;) {
#pragma unroll
          for (int i = 0; i < 8; ++i) vv[i] = al32(dp + (size_t)(i & 3) * HIDq + 16*(i >> 2));
          u32 bad = 0;
#pragma unroll
          for (int i = 0; i < 8; ++i) bad |= vv[i] ^ tag2;
          if ((bad & 0xFFFF0000u) == 0) break;
        }
#pragma unroll
        for (int j = 0; j < 2; ++j)
#pragma unroll
          for (int r = 0; r < 4; ++r) {
            union { u16 u; f16 h; } cv; cv.u = (u16)vv[j*4 + r];
            dv[j][r] = (float)cv.h;
          }
      }
      // peer slab ingest from hb2 (proven 2-slot exchange)
      {
        const u64* pp = (const u64*)&hb2[(size_t)(slot*64 + 16*g + irow) * HIDq] + (pcol >> 1);
        u64 v[4];
#pragma unroll
        for (int jj = 0; jj < 4; ++jj) v[jj] = al64(pp + jj);
        for (;;) {
          u32 bad = 0;
#pragma unroll
          for (int jj = 0; jj < 4; ++jj)
            bad |= ((u32)v[jj] ^ tagw) | ((u32)(v[jj] >> 32) ^ tagw);
          if ((bad & 0xFFFF0000u) == 0) break;
#pragma unroll
          for (int jj = 0; jj < 4; ++jj) v[jj] = al64(pp + jj);
        }
        union { u32 wd[4]; f16x8 vv; } fr;
#pragma unroll
        for (int jj = 0; jj < 4; ++jj)
          fr.wd[jj] = __builtin_amdgcn_perm((u32)(v[jj] >> 32), (u32)v[jj], 0x05040100u);
        *(f16x8*)&hL[wb][irow][pcol] = fr.vv;
      }
      __syncthreads();   // hL[wb] complete for step t+1
    }
  }
}

// ---- final: out[64,128] = h_last[64,512] @ fc_w^T + fc_b; h from tagged buffer ----
__global__ __launch_bounds__(64) void k_final(const u32* __restrict__ h, const f16* __restrict__ fw,
                                              const f16* __restrict__ fb, void* __restrict__ outv,
                                              const int* __restrict__ dmode) {
  __shared__ f16 hA[16][520];
  __shared__ f16 Bw[16][520];
  const int mb = blockIdx.x & 3, nb = blockIdx.x >> 2;
  const int lane = threadIdx.x, l15 = lane & 15, q = lane >> 4;
  for (int i = lane; i < 16 * 128; i += 64) {   // tagged u32 -> f16 (low 16)
    int r = i >> 7, c = (i & 127) * 4;
    const u64* p = (const u64*)&h[(size_t)(mb*16 + r) * 512 + c];
    u64 v0 = al64(p), v1 = al64(p + 1);
    *(u32*)&hA[r][c]     = __builtin_amdgcn_perm((u32)(v0 >> 32), (u32)v0, 0x05040100u);
    *(u32*)&hA[r][c + 2] = __builtin_amdgcn_perm((u32)(v1 >> 32), (u32)v1, 0x05040100u);
  }
  for (int i = lane; i < 16 * 64; i += 64) {
    int r = i >> 6, c = (i & 63) * 8;
    *(f16x8*)&Bw[r][c] = *(const f16x8*)&fw[(size_t)(nb*16 + r) * 512 + c];
  }
  __syncthreads();
  f32x4 acc = {};
#pragma unroll
  for (int kk = 0; kk < 16; ++kk) {
    f16x8 a = *(const f16x8*)&hA[l15][kk*32 + q*8];
    f16x8 b = *(const f16x8*)&Bw[l15][kk*32 + q*8];
    acc = __builtin_amdgcn_mfma_f32_16x16x32_f16(a, b, acc, 0, 0, 0);
  }
  float bv = (float)fb[nb*16 + l15];
  int md = *dmode;
#pragma unroll
  for (int r = 0; r < 4; ++r) {
    int idx = (mb*16 + q*4 + r) * 128 + nb*16 + l15;
    float val = acc[r] + bv;
    if (md) ((float*)outv)[idx] = val;
    else    ((u16*)outv)[idx]   = f2bf(val);
  }
}

extern "C" void kernel_launch(void* const* d_in, const int* in_sizes, int n_in,
                              void* d_out, int out_size, void* d_ws, size_t ws_size,
                              hipStream_t stream) {
  if (ws_size < 88080384ull) {
    k_zero<<<32, 256, 0, stream>>>((u16*)d_out);
    return;
  }
  char* ws = (char*)d_ws;
  // ---- control / tagged buffers ----
  u32* hb2   = (u32*)(ws + 0);           // h2 tagged, 2 slots: 256 KiB
  u32* prog  = (u32*)(ws + 262144);      // 8 u32 scan2 progress
  int* dmode = (int*)(ws + 262208);
  // ---- weights (f16) ----
  f16* Wx0f = (f16*)(ws + 262656);       // 131072 B
  f16* Uc0f = (f16*)(ws + 393728);       // 262144
  f16* Vh0f = (f16*)(ws + 655872);       // 524288
  f16* Wx1f = (f16*)(ws + 1180160);      // 262144
  f16* Uc1f = (f16*)(ws + 1442304);      // 262144
  f16* Vh1f = (f16*)(ws + 1704448);      // 524288
  f16* fcwf = (f16*)(ws + 2228736);      // 131072
  f16* bx0f = (f16*)(ws + 2359808);      // 512
  f16* bx1f = (f16*)(ws + 2360320);      // 512
  f16* fcbf = (f16*)(ws + 2360832);      // 256
  f16* Wx1T = (f16*)(ws + 2361344);      // 262144  (Wx1 transposed [512][256])
  f16* W2f  = (f16*)(ws + 2623488);      // 524288  (Uc1 @ Wx1, [512][512])
  f16* b2f  = (f16*)(ws + 3147776);      // 1024    (Uc1 @ bx1)
  // ---- big buffers (with lifetime overlays) ----
  f16* x16  = (f16*)(ws + 4194304);      // 16 MiB, dead after xp1-gemm
  u32* ring = (u32*)(ws + 4194304);      // 32 MiB: h1 ring, overlays x16+xp1
  f16* xp1  = (f16*)(ws + 20971520);     // 16 MiB, dead after ema
  f16* cb1  = (f16*)(ws + 37748736);     // 16 MiB, dead after d1-gemm
  u32* d2r  = (u32*)(ws + 37748736);     // 16 MiB: d2 ring, overlays cb1
  f16* d1   = (f16*)(ws + 54525952);     // 32 MiB, time-major [t][64][512], persists

  k_probe<<<1, 256, 0, stream>>>((const u16*)d_in[1], dmode);
  auto cvt = [&](const void* s, f16* d, int n) {
    int n8 = n / 8;
    k_cvt<<<dim3((n8 + 255) / 256), dim3(256), 0, stream>>>(s, d, n8, dmode);
  };
  cvt(d_in[0],  x16,  8388608);
  cvt(d_in[1],  Wx0f, 65536);
  cvt(d_in[2],  bx0f, 256);
  cvt(d_in[3],  Uc0f, 131072);
  cvt(d_in[4],  Vh0f, 262144);
  cvt(d_in[5],  Wx1f, 131072);
  cvt(d_in[6],  bx1f, 256);
  cvt(d_in[7],  Uc1f, 131072);
  cvt(d_in[8],  Vh1f, 262144);
  cvt(d_in[9],  fcwf, 65536);
  cvt(d_in[10], fcbf, 128);

  // layer-2 weight merge: W2 = Uc1 @ Wx1, b2 = Uc1 @ bx1
  k_tr<<<512, 256, 0, stream>>>(Wx1f, Wx1T, 256, 9);
  k_bias<<<1, 512, 0, stream>>>(Uc1f, bx1f, b2f);
  k_gemm<false, false><<<dim3(4, 4), 256, 0, stream>>>(Uc1f, Wx1T, nullptr, W2f, 512, 512, 256);

  // layer-1 front (unchanged proven path): xp1 -> EMA -> d1 (time-major)
  k_gemm<true , false><<<dim3(2, 256), 256, 0, stream>>>(x16, Wx0f, bx0f, xp1, 32768, 256, 256);
  k_ema<<<512, 128, 0, stream>>>(xp1, cb1);
  hipMemsetAsync(ws + 4194304, 0, 33554432, stream);            // h1 ring (x16,xp1 now dead)
  k_gemm<false, true ><<<dim3(4, 256), 256, 0, stream>>>(cb1, Uc0f, nullptr, d1, 32768, 512, 256);
  hipMemsetAsync(ws + 37748736, 0, 16777216, stream);           // d2 ring (cb1 now dead)
  hipMemsetAsync(ws, 0, 262176, stream);                        // hb2 + prog

  // fused pipeline: scan1 || e-GEMM/EMA || scan2
  k_mega<<<24, 512, 0, stream>>>(Vh0f, Vh1f, W2f, b2f, d1, ring, d2r, hb2, prog);

  // head: h2_511 (slot 1) in hb2 (tagged)
  k_final<<<32, 64, 0, stream>>>(hb2 + 64 * 512, fcwf, fcbf, d_out, dmode);
}

// Round 2
// 1901.141 us; speedup vs baseline: 1.4834x; 1.0145x over previous
//
#include <hip/hip_runtime.h>

// SCRN 2-layer + fc head — LAYER-PIPELINED PERSISTENT MEGA-KERNEL, round 2.
// Round-1 result: 1929 us total, k_mega 1727 us = 3.37 us/step vs 2.55 us/step for the
// standalone scan. Diagnosis: (a) e-block backpressure gate did a fresh agent-scope LLC
// load EVERY step (t>=129) -> ~0.5 us serialized on the e-stage period, making e the
// pipeline pacer; (b) scan2 serialized the d2_{t+1} poll BEFORE the hb2 peer ingest
// (sum of two LLC RTs instead of max); (c) spin loops hammer the LLC with back-to-back
// atomic loads, inflating everyone's RT. Fixes this round:
//   1. cached-progress gate in e-blocks (re-load only when cached value insufficient:
//      one LLC load per ~126 steps instead of per step)
//   2. scan2: merged d2-poll + peer-slab ingest into ONE combined revalidation wait
//   3. s_sleep(1) backoff in all spin-retry paths (first check stays immediate)
// Everything else (rings, tags, front, head) unchanged from the proven round-1 kernel.

typedef _Float16 f16;
typedef _Float16 f16x8 __attribute__((ext_vector_type(8)));
typedef _Float16 f16x2 __attribute__((ext_vector_type(2)));
typedef float f32x4 __attribute__((ext_vector_type(4)));
typedef unsigned short u16;
typedef unsigned int u32;
typedef unsigned short u16x8 __attribute__((ext_vector_type(8)));
typedef unsigned long long u64;

#define DEV __device__ __forceinline__

constexpr int Tt = 512, HIDq = 512;

DEV float bf2f(u16 u) { unsigned v = ((unsigned)u) << 16; float f; __builtin_memcpy(&f, &v, 4); return f; }
DEV u16 f2bf(float f) { unsigned u; __builtin_memcpy(&u, &f, 4); u = (u + 0x7fffu + ((u >> 16) & 1u)) >> 16; return (u16)u; }
DEV float fast_tanh(float x) {
  x = fminf(30.f, fmaxf(-30.f, x));
  float e = exp2f(x * 2.885390081777927f);   // e^(2x)
  return (e - 1.f) / (e + 1.f);
}
DEV u64 al64(const u64* p) { return __hip_atomic_load(p, __ATOMIC_RELAXED, __HIP_MEMORY_SCOPE_AGENT); }
DEV u32 al32(const u32* p) { return __hip_atomic_load(p, __ATOMIC_RELAXED, __HIP_MEMORY_SCOPE_AGENT); }
DEV void as32(u32* p, u32 v) { __hip_atomic_store(p, v, __ATOMIC_RELAXED, __HIP_MEMORY_SCOPE_AGENT); }

// ---- dtype probe: Wx0 entries bounded by 1/16; bf16 decode of f32 mantissa halves -> huge ----
__global__ void k_probe(const u16* __restrict__ w, int* __restrict__ dmode) {
  __shared__ int s;
  if (threadIdx.x == 0) s = 0;
  __syncthreads();
  int found = 0;
  for (int i = threadIdx.x; i < 8192; i += 256) {
    float v = bf2f(w[i]);
    if (fabsf(v) > 0.5f) found = 1;
  }
  if (found) atomicOr(&s, 1);
  __syncthreads();
  if (threadIdx.x == 0) *dmode = s;   // 0 = bf16 buffers, 1 = f32 buffers
}

// ---- convert n8*8 elements (bf16 or f32 per mode) -> fp16 ----
__global__ void k_cvt(const void* __restrict__ src, f16* __restrict__ dst, int n8,
                      const int* __restrict__ dmode) {
  int i = blockIdx.x * 256 + threadIdx.x;
  if (i >= n8) return;
  f16x8 o;
  if (*dmode) {
    const float4* s = (const float4*)src;
    float4 a = s[2*i], b = s[2*i+1];
    o[0]=(f16)a.x; o[1]=(f16)a.y; o[2]=(f16)a.z; o[3]=(f16)a.w;
    o[4]=(f16)b.x; o[5]=(f16)b.y; o[6]=(f16)b.z; o[7]=(f16)b.w;
  } else {
    u16x8 v = ((const u16x8*)src)[i];
#pragma unroll
    for (int j = 0; j < 8; ++j) o[j] = (f16)bf2f(v[j]);
  }
  ((f16x8*)dst)[i] = o;
}

__global__ void k_zero(u16* __restrict__ out) {  // diagnostic fallback (ws too small)
  out[blockIdx.x * 256 + threadIdx.x] = 0;
}

// ---- transpose [R][2^cshift] -> [2^cshift][R] (small weights only) ----
__global__ __launch_bounds__(256) void k_tr(const f16* __restrict__ src, f16* __restrict__ dst,
                                            int R, int cshift) {
  int idx = blockIdx.x * 256 + threadIdx.x;
  int r = idx >> cshift, c = idx & ((1 << cshift) - 1);
  dst[c * R + r] = src[idx];
}

// ---- b2[j] = sum_c Uc1[j,c] * bx1[c] ----
__global__ __launch_bounds__(512) void k_bias(const f16* __restrict__ Uc, const f16* __restrict__ bx,
                                              f16* __restrict__ out) {
  int j = threadIdx.x;
  float a = 0.f;
  for (int c = 0; c < 256; ++c) a += (float)Uc[j * 256 + c] * (float)bx[c];
  out[j] = (f16)a;
}

// ---- EMA c_t = 0.05 c_{t-1} + 0.95 xp_t ; 16-step warmup per 64-chunk (batch-major) ----
__global__ __launch_bounds__(128) void k_ema(const f16* __restrict__ xp, f16* __restrict__ c) {
  int b = blockIdx.x >> 3, chunk = blockIdx.x & 7;
  int t0 = chunk * 64;
  int ch = threadIdx.x;
  const f16x2* src = (const f16x2*)(xp + (size_t)b * Tt * 256) + ch;
  f16x2* dst = (f16x2*)(c + (size_t)b * Tt * 256) + ch;
  float c0 = 0.f, c1 = 0.f;
  int ts = (t0 >= 16) ? t0 - 16 : 0;
  for (int tt = ts; tt < t0 + 64; ++tt) {
    f16x2 v = src[(size_t)tt * 128];
    c0 = 0.05f * c0 + 0.95f * (float)v.x;
    c1 = 0.05f * c1 + 0.95f * (float)v.y;
    if (tt >= t0) { f16x2 o; o.x = (f16)c0; o.y = (f16)c1; dst[(size_t)tt * 128] = o; }
  }
}

// ---- GEMM: C = A[M,K] @ B[N,K]^T (+bias). TD: store C time-major (row b*512+t -> t*64+b) ----
template<bool HAS_BIAS, bool TD>
__global__ __launch_bounds__(256) void k_gemm(const f16* __restrict__ A, const f16* __restrict__ Bm,
                                              const f16* __restrict__ bias, f16* __restrict__ C,
                                              int M, int N, int K) {
  __shared__ f16 As[128][40];
  __shared__ f16 Bs[128][40];
  const int tid = threadIdx.x, lane = tid & 63, wv = tid >> 6;
  const int l15 = lane & 15, q = lane >> 4;
  const int wm = wv >> 1, wn = wv & 1;
  const int m0 = blockIdx.y * 128, n0 = blockIdx.x * 128;
  const int srow = tid >> 1, sseg = tid & 1;
  f32x4 acc[4][4] = {};
  const f16* ga = A  + (size_t)(m0 + srow) * K + sseg * 16;
  const f16* gb = Bm + (size_t)(n0 + srow) * K + sseg * 16;
  for (int k0 = 0; k0 < K; k0 += 32) {
    f16x8 a0 = *(const f16x8*)(ga + k0);
    f16x8 a1 = *(const f16x8*)(ga + k0 + 8);
    f16x8 b0 = *(const f16x8*)(gb + k0);
    f16x8 b1 = *(const f16x8*)(gb + k0 + 8);
    __syncthreads();
    *(f16x8*)&As[srow][sseg*16]     = a0;
    *(f16x8*)&As[srow][sseg*16 + 8] = a1;
    *(f16x8*)&Bs[srow][sseg*16]     = b0;
    *(f16x8*)&Bs[srow][sseg*16 + 8] = b1;
    __syncthreads();
    f16x8 af[4], bf[4];
#pragma unroll
    for (int i = 0; i < 4; ++i) af[i] = *(const f16x8*)&As[wm*64 + i*16 + l15][q*8];
#pragma unroll
    for (int i = 0; i < 4; ++i) bf[i] = *(const f16x8*)&Bs[wn*64 + i*16 + l15][q*8];
#pragma unroll
    for (int i = 0; i < 4; ++i)
#pragma unroll
      for (int j = 0; j < 4; ++j)
        acc[i][j] = __builtin_amdgcn_mfma_f32_16x16x32_f16(af[i], bf[j], acc[i][j], 0, 0, 0);
  }
#pragma unroll
  for (int j = 0; j < 4; ++j) {
    int col = n0 + wn*64 + j*16 + l15;
    float bv = HAS_BIAS ? (float)bias[col] : 0.f;
#pragma unroll
    for (int i = 0; i < 4; ++i)
#pragma unroll
      for (int r = 0; r < 4; ++r) {
        int row = m0 + wm*64 + i*16 + q*4 + r;
        size_t orow = TD ? (size_t)((row & 511) * 64 + (row >> 9)) : (size_t)row;
        C[orow * N + col] = (f16)(acc[i][j][r] + bv);
      }
  }
}

// ---- persistent mega-kernel: scan1 (0-7) | e-GEMM+EMA (8-15) | scan2 (16-23) ----
// ring : h1 tagged, 256 slots x [64][512] u32 (slot = t & 255, tag = t+1)
// d2r  : d2 tagged, 128 slots x [64][512] u32 (slot = t & 127, tag = t+1)
// hb2  : h2 tagged, 2 slots (identical to proven k_scan exchange)
// prog : 8 u32, scan2 block sb writes t after d2_t consumed (e-block backpressure)
__global__ __launch_bounds__(512, 2) void k_mega(const f16* __restrict__ Vh0,
                                                 const f16* __restrict__ Vh1,
                                                 const f16* __restrict__ W2,
                                                 const f16* __restrict__ b2,
                                                 const f16* __restrict__ d1,
                                                 u32* __restrict__ ring,
                                                 u32* __restrict__ d2r,
                                                 u32* __restrict__ hb2,
                                                 u32* __restrict__ prog) {
  __shared__ f16 hL[2][16][520];
  const int bb = blockIdx.x;
  const int tid = threadIdx.x, w = tid >> 6, lane = tid & 63;
  const int l15 = lane & 15, q = lane >> 4;

  if (bb < 8) {
    // ================= scan1: h1_t = tanh(d1_t + h1_{t-1} @ Vh0^T) -> ring ==============
    const int hf = bb & 1, g = bb >> 1;
    const int colbase = 256*hf + 32*w;
    f16x8 Bf[2][16];
#pragma unroll
    for (int j = 0; j < 2; ++j)
#pragma unroll
      for (int kk = 0; kk < 16; ++kk)
        Bf[j][kk] = *(const f16x8*)&Vh0[(size_t)(colbase + 16*j + l15) * HIDq + kk*32 + q*8];
    for (int i = tid; i < 1024; i += 512) {
      int r = i >> 6, c = (i & 63) * 8;
      f16x8 z = {};
      *(f16x8*)&hL[0][r][c] = z;
    }
    float dv[2][4];
#pragma unroll
    for (int j = 0; j < 2; ++j)
#pragma unroll
      for (int r = 0; r < 4; ++r)
        dv[j][r] = (float)d1[(size_t)(16*g + q*4 + r) * HIDq + colbase + 16*j + l15];
    __syncthreads();
    const int irow = tid >> 5, ic8 = (tid & 31) * 8;
    const int pcol = 256*(hf ^ 1) + ic8;

    for (int t = 0; t < Tt; ++t) {
      const int rb = t & 1, wb = rb ^ 1;
      u32* rslot = ring + (size_t)(t & 255) * 32768;
      f32x4 a00 = {}, a01 = {}, a10 = {}, a11 = {};
#pragma unroll
      for (int kk = 0; kk < 16; ++kk) {
        f16x8 a = *(const f16x8*)&hL[rb][l15][kk*32 + q*8];
        if (kk & 1) {
          a01 = __builtin_amdgcn_mfma_f32_16x16x32_f16(a, Bf[0][kk], a01, 0, 0, 0);
          a11 = __builtin_amdgcn_mfma_f32_16x16x32_f16(a, Bf[1][kk], a11, 0, 0, 0);
        } else {
          a00 = __builtin_amdgcn_mfma_f32_16x16x32_f16(a, Bf[0][kk], a00, 0, 0, 0);
          a10 = __builtin_amdgcn_mfma_f32_16x16x32_f16(a, Bf[1][kk], a10, 0, 0, 0);
        }
      }
      const u32 tagw = (u32)(t + 1) << 16;
      u16 hbits[2][4];
#pragma unroll
      for (int j = 0; j < 2; ++j) {
        f32x4 s = j ? (a10 + a11) : (a00 + a01);
#pragma unroll
        for (int r = 0; r < 4; ++r) {
          float z = s[r] + dv[j][r];
          union { f16 h; u16 u; } cv; cv.h = (f16)fast_tanh(z);
          hbits[j][r] = cv.u;
          as32(&rslot[(size_t)(16*g + q*4 + r) * HIDq + colbase + 16*j + l15],
               tagw | (u32)cv.u);
        }
      }
#pragma unroll
      for (int j = 0; j < 2; ++j)
#pragma unroll
        for (int r = 0; r < 4; ++r) {
          union { u16 u; f16 h; } cv; cv.u = hbits[j][r];
          hL[wb][q*4 + r][colbase + 16*j + l15] = cv.h;
        }
      if (t < Tt - 1) {
#pragma unroll
        for (int j = 0; j < 2; ++j)
#pragma unroll
          for (int r = 0; r < 4; ++r)
            dv[j][r] = (float)d1[((size_t)(t+1)*64 + 16*g + q*4 + r) * HIDq + colbase + 16*j + l15];
      }
      // peer slab ingest (combined load + combined revalidation, s_sleep backoff)
      {
        const u64* pp = (const u64*)(rslot + (size_t)(16*g + irow) * HIDq) + (pcol >> 1);
        u64 v[4];
#pragma unroll
        for (int jj = 0; jj < 4; ++jj) v[jj] = al64(pp + jj);
        for (;;) {
          u32 bad = 0;
#pragma unroll
          for (int jj = 0; jj < 4; ++jj)
            bad |= ((u32)v[jj] ^ tagw) | ((u32)(v[jj] >> 32) ^ tagw);
          if ((bad & 0xFFFF0000u) == 0) break;
          __builtin_amdgcn_s_sleep(1);
#pragma unroll
          for (int jj = 0; jj < 4; ++jj) v[jj] = al64(pp + jj);
        }
        union { u32 wd[4]; f16x8 vv; } fr;
#pragma unroll
        for (int jj = 0; jj < 4; ++jj)
          fr.wd[jj] = __builtin_amdgcn_perm((u32)(v[jj] >> 32), (u32)v[jj], 0x05040100u);
        *(f16x8*)&hL[wb][irow][pcol] = fr.vv;
      }
      __syncthreads();
    }

  } else if (bb < 16) {
    // ================= e-block: d2_t = 0.05 d2 + 0.95 (h1_t @ W2^T + b2) -> d2r ==========
    const int eb = bb - 8, hf = eb & 1, g = eb >> 1;
    const int colbase = 256*hf + 32*w;
    f16x8 Bf[2][16];
#pragma unroll
    for (int j = 0; j < 2; ++j)
#pragma unroll
      for (int kk = 0; kk < 16; ++kk)
        Bf[j][kk] = *(const f16x8*)&W2[(size_t)(colbase + 16*j + l15) * HIDq + kk*32 + q*8];
    float bv[2] = { (float)b2[colbase + l15], (float)b2[colbase + 16 + l15] };
    float ed[2][4] = {};
    const int irow = tid >> 5, icol = (tid & 31) * 16;   // 16 rows x 32 thr x 16 u32-cols
    int eprog_c = 0;   // cached scan2 progress (tid0 only meaningful); one LLC load / ~126 steps

    for (int t = 0; t < Tt; ++t) {
      // backpressure: about to overwrite d2_{t-128}; partner must have consumed it.
      // CACHED gate: only hit the LLC when the cached value is actually insufficient.
      if (tid == 0 && t >= 129 && eprog_c < t - 128) {
        for (;;) {
          eprog_c = (int)al32(&prog[eb]);
          if (eprog_c >= t - 128) break;
          __builtin_amdgcn_s_sleep(1);
        }
      }
      const u32 tagw = (u32)(t + 1) << 16;
      // ingest h1_t (full 512 cols for our 16 rows): 8 u64/thread, combined revalidation
      {
        const u64* pp = (const u64*)(ring + (size_t)(t & 255) * 32768
                          + (size_t)(16*g + irow) * HIDq) + (icol >> 1);
        u64 v[8];
#pragma unroll
        for (int jj = 0; jj < 8; ++jj) v[jj] = al64(pp + jj);
        for (;;) {
          u32 bad = 0;
#pragma unroll
          for (int jj = 0; jj < 8; ++jj)
            bad |= ((u32)v[jj] ^ tagw) | ((u32)(v[jj] >> 32) ^ tagw);
          if ((bad & 0xFFFF0000u) == 0) break;
          __builtin_amdgcn_s_sleep(1);
#pragma unroll
          for (int jj = 0; jj < 8; ++jj) v[jj] = al64(pp + jj);
        }
        union { u32 wd[8]; f16x8 vv[2]; } fr;
#pragma unroll
        for (int jj = 0; jj < 8; ++jj)
          fr.wd[jj] = __builtin_amdgcn_perm((u32)(v[jj] >> 32), (u32)v[jj], 0x05040100u);
        *(f16x8*)&hL[t & 1][irow][icol]     = fr.vv[0];
        *(f16x8*)&hL[t & 1][irow][icol + 8] = fr.vv[1];
      }
      __syncthreads();   // hL[t&1] complete; also orders publish after tid0's gate
      f32x4 a00 = {}, a01 = {}, a10 = {}, a11 = {};
#pragma unroll
      for (int kk = 0; kk < 16; ++kk) {
        f16x8 a = *(const f16x8*)&hL[t & 1][l15][kk*32 + q*8];
        if (kk & 1) {
          a01 = __builtin_amdgcn_mfma_f32_16x16x32_f16(a, Bf[0][kk], a01, 0, 0, 0);
          a11 = __builtin_amdgcn_mfma_f32_16x16x32_f16(a, Bf[1][kk], a11, 0, 0, 0);
        } else {
          a00 = __builtin_amdgcn_mfma_f32_16x16x32_f16(a, Bf[0][kk], a00, 0, 0, 0);
          a10 = __builtin_amdgcn_mfma_f32_16x16x32_f16(a, Bf[1][kk], a10, 0, 0, 0);
        }
      }
      u32* dslot = d2r + (size_t)(t & 127) * 32768;
#pragma unroll
      for (int j = 0; j < 2; ++j) {
        f32x4 s = j ? (a10 + a11) : (a00 + a01);
#pragma unroll
        for (int r = 0; r < 4; ++r) {
          ed[j][r] = 0.05f * ed[j][r] + 0.95f * (s[r] + bv[j]);
          union { f16 h; u16 u; } cv; cv.h = (f16)ed[j][r];
          as32(&dslot[(size_t)(16*g + q*4 + r) * HIDq + colbase + 16*j + l15],
               tagw | (u32)cv.u);
        }
      }
      // no 2nd barrier needed: next iter writes hL[(t+1)&1]; the single barrier keeps
      // waves <=1 step apart, so hL[t&1] can't be overwritten while still being read.
    }

  } else {
    // ================= scan2: h2_t = tanh(d2_t + h2_{t-1} @ Vh1^T) -> hb2 ===============
    const int sb = bb - 16, hf = sb & 1, g = sb >> 1;
    const int colbase = 256*hf + 32*w;
    f16x8 Bf[2][16];
#pragma unroll
    for (int j = 0; j < 2; ++j)
#pragma unroll
      for (int kk = 0; kk < 16; ++kk)
        Bf[j][kk] = *(const f16x8*)&Vh1[(size_t)(colbase + 16*j + l15) * HIDq + kk*32 + q*8];
    for (int i = tid; i < 1024; i += 512) {
      int r = i >> 6, c = (i & 63) * 8;
      f16x8 z = {};
      *(f16x8*)&hL[0][r][c] = z;
    }
    // d2_0 tagged poll (tag 1, slot 0) — long pipeline-fill wait, sleep in retry
    float dv[2][4];
    {
      const u32 tag2 = 1u << 16;
      const u32* dp = d2r + (size_t)(16*g + q*4) * HIDq + colbase + l15;
      u32 vv[8];
      for (;;) {
#pragma unroll
        for (int i = 0; i < 8; ++i) vv[i] = al32(dp + (size_t)(i & 3) * HIDq + 16*(i >> 2));
        u32 bad = 0;
#pragma unroll
        for (int i = 0; i < 8; ++i) bad |= vv[i] ^ tag2;
        if ((bad & 0xFFFF0000u) == 0) break;
        __builtin_amdgcn_s_sleep(1);
      }
#pragma unroll
      for (int j = 0; j < 2; ++j)
#pragma unroll
        for (int r = 0; r < 4; ++r) {
          union { u16 u; f16 h; } cv; cv.u = (u16)vv[j*4 + r];
          dv[j][r] = (float)cv.h;
        }
    }
    __syncthreads();
    const int irow = tid >> 5, ic8 = (tid & 31) * 8;
    const int pcol = 256*(hf ^ 1) + ic8;

    for (int t = 0; t < Tt; ++t) {
      const int rb = t & 1, wb = rb ^ 1, slot = t & 1;
      if (tid == 0 && t > 0) as32(&prog[sb], (u32)t);   // d2_t consumed last iter (post-barrier)
      f32x4 a00 = {}, a01 = {}, a10 = {}, a11 = {};
#pragma unroll
      for (int kk = 0; kk < 16; ++kk) {
        f16x8 a = *(const f16x8*)&hL[rb][l15][kk*32 + q*8];
        if (kk & 1) {
          a01 = __builtin_amdgcn_mfma_f32_16x16x32_f16(a, Bf[0][kk], a01, 0, 0, 0);
          a11 = __builtin_amdgcn_mfma_f32_16x16x32_f16(a, Bf[1][kk], a11, 0, 0, 0);
        } else {
          a00 = __builtin_amdgcn_mfma_f32_16x16x32_f16(a, Bf[0][kk], a00, 0, 0, 0);
          a10 = __builtin_amdgcn_mfma_f32_16x16x32_f16(a, Bf[1][kk], a10, 0, 0, 0);
        }
      }
      const u32 tagw = (u32)(t + 1) << 16;
      u16 hbits[2][4];
#pragma unroll
      for (int j = 0; j < 2; ++j) {
        f32x4 s = j ? (a10 + a11) : (a00 + a01);
#pragma unroll
        for (int r = 0; r < 4; ++r) {
          float z = s[r] + dv[j][r];
          union { f16 h; u16 u; } cv; cv.h = (f16)fast_tanh(z);
          hbits[j][r] = cv.u;
          as32(&hb2[(size_t)(slot*64 + 16*g + q*4 + r) * HIDq + colbase + 16*j + l15],
               tagw | (u32)cv.u);
        }
      }
#pragma unroll
      for (int j = 0; j < 2; ++j)
#pragma unroll
        for (int r = 0; r < 4; ++r) {
          union { u16 u; f16 h; } cv; cv.u = hbits[j][r];
          hL[wb][q*4 + r][colbase + 16*j + l15] = cv.h;
        }

      // MERGED wait: d2_{t+1} poll + hb2 peer-slab ingest in ONE combined revalidation
      // (round-1 had them serial: sum of two LLC RTs; now it's the max).
      {
        const bool have_d = (t < Tt - 1);
        const u32 tag2 = (u32)(t + 2) << 16;
        const u32* dp = d2r + (size_t)((t + 1) & 127) * 32768
                      + (size_t)(16*g + q*4) * HIDq + colbase + l15;
        const u64* pp = (const u64*)&hb2[(size_t)(slot*64 + 16*g + irow) * HIDq] + (pcol >> 1);
        u32 vv[8];
        u64 v[4];
        if (have_d) {
#pragma unroll
          for (int i = 0; i < 8; ++i) vv[i] = al32(dp + (size_t)(i & 3) * HIDq + 16*(i >> 2));
        }
#pragma unroll
        for (int jj = 0; jj < 4; ++jj) v[jj] = al64(pp + jj);
        for (;;) {
          u32 badp = 0;
#pragma unroll
          for (int jj = 0; jj < 4; ++jj)
            badp |= ((u32)v[jj] ^ tagw) | ((u32)(v[jj] >> 32) ^ tagw);
          badp &= 0xFFFF0000u;
          u32 badd = 0;
          if (have_d) {
#pragma unroll
            for (int i = 0; i < 8; ++i) badd |= vv[i] ^ tag2;
            badd &= 0xFFFF0000u;
          }
          if (!(badp | badd)) break;
          __builtin_amdgcn_s_sleep(1);
          if (badp) {
#pragma unroll
            for (int jj = 0; jj < 4; ++jj) v[jj] = al64(pp + jj);
          }
          if (badd) {
#pragma unroll
            for (int i = 0; i < 8; ++i) vv[i] = al32(dp + (size_t)(i & 3) * HIDq + 16*(i >> 2));
          }
        }
        if (have_d) {
#pragma unroll
          for (int j = 0; j < 2; ++j)
#pragma unroll
            for (int r = 0; r < 4; ++r) {
              union { u16 u; f16 h; } cv; cv.u = (u16)vv[j*4 + r];
              dv[j][r] = (float)cv.h;
            }
        }
        union { u32 wd[4]; f16x8 vr; } fr;
#pragma unroll
        for (int jj = 0; jj < 4; ++jj)
          fr.wd[jj] = __builtin_amdgcn_perm((u32)(v[jj] >> 32), (u32)v[jj], 0x05040100u);
        *(f16x8*)&hL[wb][irow][pcol] = fr.vr;
      }
      __syncthreads();   // hL[wb] complete for step t+1
    }
  }
}

// ---- final: out[64,128] = h_last[64,512] @ fc_w^T + fc_b; h from tagged buffer ----
__global__ __launch_bounds__(64) void k_final(const u32* __restrict__ h, const f16* __restrict__ fw,
                                              const f16* __restrict__ fb, void* __restrict__ outv,
                                              const int* __restrict__ dmode) {
  __shared__ f16 hA[16][520];
  __shared__ f16 Bw[16][520];
  const int mb = blockIdx.x & 3, nb = blockIdx.x >> 2;
  const int lane = threadIdx.x, l15 = lane & 15, q = lane >> 4;
  for (int i = lane; i < 16 * 128; i += 64) {   // tagged u32 -> f16 (low 16)
    int r = i >> 7, c = (i & 127) * 4;
    const u64* p = (const u64*)&h[(size_t)(mb*16 + r) * 512 + c];
    u64 v0 = al64(p), v1 = al64(p + 1);
    *(u32*)&hA[r][c]     = __builtin_amdgcn_perm((u32)(v0 >> 32), (u32)v0, 0x05040100u);
    *(u32*)&hA[r][c + 2] = __builtin_amdgcn_perm((u32)(v1 >> 32), (u32)v1, 0x05040100u);
  }
  for (int i = lane; i < 16 * 64; i += 64) {
    int r = i >> 6, c = (i & 63) * 8;
    *(f16x8*)&Bw[r][c] = *(const f16x8*)&fw[(size_t)(nb*16 + r) * 512 + c];
  }
  __syncthreads();
  f32x4 acc = {};
#pragma unroll
  for (int kk = 0; kk < 16; ++kk) {
    f16x8 a = *(const f16x8*)&hA[l15][kk*32 + q*8];
    f16x8 b = *(const f16x8*)&Bw[l15][kk*32 + q*8];
    acc = __builtin_amdgcn_mfma_f32_16x16x32_f16(a, b, acc, 0, 0, 0);
  }
  float bv = (float)fb[nb*16 + l15];
  int md = *dmode;
#pragma unroll
  for (int r = 0; r < 4; ++r) {
    int idx = (mb*16 + q*4 + r) * 128 + nb*16 + l15;
    float val = acc[r] + bv;
    if (md) ((float*)outv)[idx] = val;
    else    ((u16*)outv)[idx]   = f2bf(val);
  }
}

extern "C" void kernel_launch(void* const* d_in, const int* in_sizes, int n_in,
                              void* d_out, int out_size, void* d_ws, size_t ws_size,
                              hipStream_t stream) {
  if (ws_size < 88080384ull) {
    k_zero<<<32, 256, 0, stream>>>((u16*)d_out);
    return;
  }
  char* ws = (char*)d_ws;
  // ---- control / tagged buffers ----
  u32* hb2   = (u32*)(ws + 0);           // h2 tagged, 2 slots: 256 KiB
  u32* prog  = (u32*)(ws + 262144);      // 8 u32 scan2 progress
  int* dmode = (int*)(ws + 262208);
  // ---- weights (f16) ----
  f16* Wx0f = (f16*)(ws + 262656);       // 131072 B
  f16* Uc0f = (f16*)(ws + 393728);       // 262144
  f16* Vh0f = (f16*)(ws + 655872);       // 524288
  f16* Wx1f = (f16*)(ws + 1180160);      // 262144
  f16* Uc1f = (f16*)(ws + 1442304);      // 262144
  f16* Vh1f = (f16*)(ws + 1704448);      // 524288
  f16* fcwf = (f16*)(ws + 2228736);      // 131072
  f16* bx0f = (f16*)(ws + 2359808);      // 512
  f16* bx1f = (f16*)(ws + 2360320);      // 512
  f16* fcbf = (f16*)(ws + 2360832);      // 256
  f16* Wx1T = (f16*)(ws + 2361344);      // 262144  (Wx1 transposed [512][256])
  f16* W2f  = (f16*)(ws + 2623488);      // 524288  (Uc1 @ Wx1, [512][512])
  f16* b2f  = (f16*)(ws + 3147776);      // 1024    (Uc1 @ bx1)
  // ---- big buffers (with lifetime overlays) ----
  f16* x16  = (f16*)(ws + 4194304);      // 16 MiB, dead after xp1-gemm
  u32* ring = (u32*)(ws + 4194304);      // 32 MiB: h1 ring, overlays x16+xp1
  f16* xp1  = (f16*)(ws + 20971520);     // 16 MiB, dead after ema
  f16* cb1  = (f16*)(ws + 37748736);     // 16 MiB, dead after d1-gemm
  u32* d2r  = (u32*)(ws + 37748736);     // 16 MiB: d2 ring, overlays cb1
  f16* d1   = (f16*)(ws + 54525952);     // 32 MiB, time-major [t][64][512], persists

  k_probe<<<1, 256, 0, stream>>>((const u16*)d_in[1], dmode);
  auto cvt = [&](const void* s, f16* d, int n) {
    int n8 = n / 8;
    k_cvt<<<dim3((n8 + 255) / 256), dim3(256), 0, stream>>>(s, d, n8, dmode);
  };
  cvt(d_in[0],  x16,  8388608);
  cvt(d_in[1],  Wx0f, 65536);
  cvt(d_in[2],  bx0f, 256);
  cvt(d_in[3],  Uc0f, 131072);
  cvt(d_in[4],  Vh0f, 262144);
  cvt(d_in[5],  Wx1f, 131072);
  cvt(d_in[6],  bx1f, 256);
  cvt(d_in[7],  Uc1f, 131072);
  cvt(d_in[8],  Vh1f, 262144);
  cvt(d_in[9],  fcwf, 65536);
  cvt(d_in[10], fcbf, 128);

  // layer-2 weight merge: W2 = Uc1 @ Wx1, b2 = Uc1 @ bx1
  k_tr<<<512, 256, 0, stream>>>(Wx1f, Wx1T, 256, 9);
  k_bias<<<1, 512, 0, stream>>>(Uc1f, bx1f, b2f);
  k_gemm<false, false><<<dim3(4, 4), 256, 0, stream>>>(Uc1f, Wx1T, nullptr, W2f, 512, 512, 256);

  // layer-1 front (unchanged proven path): xp1 -> EMA -> d1 (time-major)
  k_gemm<true , false><<<dim3(2, 256), 256, 0, stream>>>(x16, Wx0f, bx0f, xp1, 32768, 256, 256);
  k_ema<<<512, 128, 0, stream>>>(xp1, cb1);
  hipMemsetAsync(ws + 4194304, 0, 33554432, stream);            // h1 ring (x16,xp1 now dead)
  k_gemm<false, true ><<<dim3(4, 256), 256, 0, stream>>>(cb1, Uc0f, nullptr, d1, 32768, 512, 256);
  hipMemsetAsync(ws + 37748736, 0, 16777216, stream);           // d2 ring (cb1 now dead)
  hipMemsetAsync(ws, 0, 262176, stream);                        // hb2 + prog

  // fused pipeline: scan1 || e-GEMM/EMA || scan2
  k_mega<<<24, 512, 0, stream>>>(Vh0f, Vh1f, W2f, b2f, d1, ring, d2r, hb2, prog);

  // head: h2_511 (slot 1) in hb2 (tagged)
  k_final<<<32, 64, 0, stream>>>(hb2 + 64 * 512, fcwf, fcbf, d_out, dmode);
}

// Round 3
// 1826.170 us; speedup vs baseline: 1.5443x; 1.0411x over previous
//
#include <hip/hip_runtime.h>

// SCRN 2-layer + fc head — LAYER-PIPELINED PERSISTENT MEGA-KERNEL, round 3.
// Round-2 post-mortem: gate/merged-wait fixes were neutral (1727->1704). Counters show the
// real pacer: FETCH 177 MB ~= all consumed published data -> every tagged poll MISSES the
// LLC and fetches DRAM. Cause: deep rings (256/128 slots, 32/16 MiB) mean each step's slot
// lines were last touched ~800 us ago -> cold. The standalone scan's 2.55 us/step relied on
// a HOT 2-slot buffer; mega rerouted scan1's own peer exchange through the cold ring ->
// +0.8 us DRAM allocate/fetch on scan1's publish->discover cycle -> scan1 paces 3.33.
// Fix this round: rings shrink to 32 slots (4 MiB each, LLC-resident; lines re-touched
// every ~80 us). Producer backpressure gates (amortized, cached):
//   scan1 gates on eprog (min of both e-blocks per group; one u64 LLC load / ~28 steps,
//          ordered before next publish by the loop-end barrier)
//   e     gates on prog (scan2 progress, as before, window 128->32)
// Gate chain references progress >=30 steps older than the gater -> deadlock-free.
// Everything else (exchange protocol, front, head) unchanged.

typedef _Float16 f16;
typedef _Float16 f16x8 __attribute__((ext_vector_type(8)));
typedef _Float16 f16x2 __attribute__((ext_vector_type(2)));
typedef float f32x4 __attribute__((ext_vector_type(4)));
typedef unsigned short u16;
typedef unsigned int u32;
typedef unsigned short u16x8 __attribute__((ext_vector_type(8)));
typedef unsigned long long u64;

#define DEV __device__ __forceinline__

constexpr int Tt = 512, HIDq = 512;
constexpr int RS = 32;   // h1 ring slots  (4 MiB)
constexpr int DSd = 32;  // d2 ring slots  (4 MiB)

DEV float bf2f(u16 u) { unsigned v = ((unsigned)u) << 16; float f; __builtin_memcpy(&f, &v, 4); return f; }
DEV u16 f2bf(float f) { unsigned u; __builtin_memcpy(&u, &f, 4); u = (u + 0x7fffu + ((u >> 16) & 1u)) >> 16; return (u16)u; }
DEV float fast_tanh(float x) {
  x = fminf(30.f, fmaxf(-30.f, x));
  float e = exp2f(x * 2.885390081777927f);   // e^(2x)
  return (e - 1.f) / (e + 1.f);
}
DEV u64 al64(const u64* p) { return __hip_atomic_load(p, __ATOMIC_RELAXED, __HIP_MEMORY_SCOPE_AGENT); }
DEV u32 al32(const u32* p) { return __hip_atomic_load(p, __ATOMIC_RELAXED, __HIP_MEMORY_SCOPE_AGENT); }
DEV void as32(u32* p, u32 v) { __hip_atomic_store(p, v, __ATOMIC_RELAXED, __HIP_MEMORY_SCOPE_AGENT); }

// ---- dtype probe: Wx0 entries bounded by 1/16; bf16 decode of f32 mantissa halves -> huge ----
__global__ void k_probe(const u16* __restrict__ w, int* __restrict__ dmode) {
  __shared__ int s;
  if (threadIdx.x == 0) s = 0;
  __syncthreads();
  int found = 0;
  for (int i = threadIdx.x; i < 8192; i += 256) {
    float v = bf2f(w[i]);
    if (fabsf(v) > 0.5f) found = 1;
  }
  if (found) atomicOr(&s, 1);
  __syncthreads();
  if (threadIdx.x == 0) *dmode = s;   // 0 = bf16 buffers, 1 = f32 buffers
}

// ---- convert n8*8 elements (bf16 or f32 per mode) -> fp16 ----
__global__ void k_cvt(const void* __restrict__ src, f16* __restrict__ dst, int n8,
                      const int* __restrict__ dmode) {
  int i = blockIdx.x * 256 + threadIdx.x;
  if (i >= n8) return;
  f16x8 o;
  if (*dmode) {
    const float4* s = (const float4*)src;
    float4 a = s[2*i], b = s[2*i+1];
    o[0]=(f16)a.x; o[1]=(f16)a.y; o[2]=(f16)a.z; o[3]=(f16)a.w;
    o[4]=(f16)b.x; o[5]=(f16)b.y; o[6]=(f16)b.z; o[7]=(f16)b.w;
  } else {
    u16x8 v = ((const u16x8*)src)[i];
#pragma unroll
    for (int j = 0; j < 8; ++j) o[j] = (f16)bf2f(v[j]);
  }
  ((f16x8*)dst)[i] = o;
}

__global__ void k_zero(u16* __restrict__ out) {  // diagnostic fallback (ws too small)
  out[blockIdx.x * 256 + threadIdx.x] = 0;
}

// ---- transpose [R][2^cshift] -> [2^cshift][R] (small weights only) ----
__global__ __launch_bounds__(256) void k_tr(const f16* __restrict__ src, f16* __restrict__ dst,
                                            int R, int cshift) {
  int idx = blockIdx.x * 256 + threadIdx.x;
  int r = idx >> cshift, c = idx & ((1 << cshift) - 1);
  dst[c * R + r] = src[idx];
}

// ---- b2[j] = sum_c Uc1[j,c] * bx1[c] ----
__global__ __launch_bounds__(512) void k_bias(const f16* __restrict__ Uc, const f16* __restrict__ bx,
                                              f16* __restrict__ out) {
  int j = threadIdx.x;
  float a = 0.f;
  for (int c = 0; c < 256; ++c) a += (float)Uc[j * 256 + c] * (float)bx[c];
  out[j] = (f16)a;
}

// ---- EMA c_t = 0.05 c_{t-1} + 0.95 xp_t ; 16-step warmup per 64-chunk (batch-major) ----
__global__ __launch_bounds__(128) void k_ema(const f16* __restrict__ xp, f16* __restrict__ c) {
  int b = blockIdx.x >> 3, chunk = blockIdx.x & 7;
  int t0 = chunk * 64;
  int ch = threadIdx.x;
  const f16x2* src = (const f16x2*)(xp + (size_t)b * Tt * 256) + ch;
  f16x2* dst = (f16x2*)(c + (size_t)b * Tt * 256) + ch;
  float c0 = 0.f, c1 = 0.f;
  int ts = (t0 >= 16) ? t0 - 16 : 0;
  for (int tt = ts; tt < t0 + 64; ++tt) {
    f16x2 v = src[(size_t)tt * 128];
    c0 = 0.05f * c0 + 0.95f * (float)v.x;
    c1 = 0.05f * c1 + 0.95f * (float)v.y;
    if (tt >= t0) { f16x2 o; o.x = (f16)c0; o.y = (f16)c1; dst[(size_t)tt * 128] = o; }
  }
}

// ---- GEMM: C = A[M,K] @ B[N,K]^T (+bias). TD: store C time-major (row b*512+t -> t*64+b) ----
template<bool HAS_BIAS, bool TD>
__global__ __launch_bounds__(256) void k_gemm(const f16* __restrict__ A, const f16* __restrict__ Bm,
                                              const f16* __restrict__ bias, f16* __restrict__ C,
                                              int M, int N, int K) {
  __shared__ f16 As[128][40];
  __shared__ f16 Bs[128][40];
  const int tid = threadIdx.x, lane = tid & 63, wv = tid >> 6;
  const int l15 = lane & 15, q = lane >> 4;
  const int wm = wv >> 1, wn = wv & 1;
  const int m0 = blockIdx.y * 128, n0 = blockIdx.x * 128;
  const int srow = tid >> 1, sseg = tid & 1;
  f32x4 acc[4][4] = {};
  const f16* ga = A  + (size_t)(m0 + srow) * K + sseg * 16;
  const f16* gb = Bm + (size_t)(n0 + srow) * K + sseg * 16;
  for (int k0 = 0; k0 < K; k0 += 32) {
    f16x8 a0 = *(const f16x8*)(ga + k0);
    f16x8 a1 = *(const f16x8*)(ga + k0 + 8);
    f16x8 b0 = *(const f16x8*)(gb + k0);
    f16x8 b1 = *(const f16x8*)(gb + k0 + 8);
    __syncthreads();
    *(f16x8*)&As[srow][sseg*16]     = a0;
    *(f16x8*)&As[srow][sseg*16 + 8] = a1;
    *(f16x8*)&Bs[srow][sseg*16]     = b0;
    *(f16x8*)&Bs[srow][sseg*16 + 8] = b1;
    __syncthreads();
    f16x8 af[4], bf[4];
#pragma unroll
    for (int i = 0; i < 4; ++i) af[i] = *(const f16x8*)&As[wm*64 + i*16 + l15][q*8];
#pragma unroll
    for (int i = 0; i < 4; ++i) bf[i] = *(const f16x8*)&Bs[wn*64 + i*16 + l15][q*8];
#pragma unroll
    for (int i = 0; i < 4; ++i)
#pragma unroll
      for (int j = 0; j < 4; ++j)
        acc[i][j] = __builtin_amdgcn_mfma_f32_16x16x32_f16(af[i], bf[j], acc[i][j], 0, 0, 0);
  }
#pragma unroll
  for (int j = 0; j < 4; ++j) {
    int col = n0 + wn*64 + j*16 + l15;
    float bv = HAS_BIAS ? (float)bias[col] : 0.f;
#pragma unroll
    for (int i = 0; i < 4; ++i)
#pragma unroll
      for (int r = 0; r < 4; ++r) {
        int row = m0 + wm*64 + i*16 + q*4 + r;
        size_t orow = TD ? (size_t)((row & 511) * 64 + (row >> 9)) : (size_t)row;
        C[orow * N + col] = (f16)(acc[i][j][r] + bv);
      }
  }
}

// ---- persistent mega-kernel: scan1 (0-7) | e-GEMM+EMA (8-15) | scan2 (16-23) ----
// ring : h1 tagged, RS=32 slots x [64][512] u32 (slot = t & 31, tag = t+1) — LLC-hot
// d2r  : d2 tagged, DS=32 slots x [64][512] u32 (slot = t & 31, tag = t+1) — LLC-hot
// hb2  : h2 tagged, 2 slots (proven hot exchange)
// prog : 8 u32, scan2 block sb writes t at top of step t (d2_t consumed)   -> gates e
// eprog: 8 u32, e-block eb writes t at top of step t (h1_{t-1} consumed)   -> gates scan1
__global__ __launch_bounds__(512, 2) void k_mega(const f16* __restrict__ Vh0,
                                                 const f16* __restrict__ Vh1,
                                                 const f16* __restrict__ W2,
                                                 const f16* __restrict__ b2,
                                                 const f16* __restrict__ d1,
                                                 u32* __restrict__ ring,
                                                 u32* __restrict__ d2r,
                                                 u32* __restrict__ hb2,
                                                 u32* __restrict__ prog,
                                                 u32* __restrict__ eprog) {
  __shared__ f16 hL[2][16][520];
  const int bb = blockIdx.x;
  const int tid = threadIdx.x, w = tid >> 6, lane = tid & 63;
  const int l15 = lane & 15, q = lane >> 4;

  if (bb < 8) {
    // ================= scan1: h1_t = tanh(d1_t + h1_{t-1} @ Vh0^T) -> ring ==============
    const int hf = bb & 1, g = bb >> 1;
    const int colbase = 256*hf + 32*w;
    f16x8 Bf[2][16];
#pragma unroll
    for (int j = 0; j < 2; ++j)
#pragma unroll
      for (int kk = 0; kk < 16; ++kk)
        Bf[j][kk] = *(const f16x8*)&Vh0[(size_t)(colbase + 16*j + l15) * HIDq + kk*32 + q*8];
    for (int i = tid; i < 1024; i += 512) {
      int r = i >> 6, c = (i & 63) * 8;
      f16x8 z = {};
      *(f16x8*)&hL[0][r][c] = z;
    }
    float dv[2][4];
#pragma unroll
    for (int j = 0; j < 2; ++j)
#pragma unroll
      for (int r = 0; r < 4; ++r)
        dv[j][r] = (float)d1[(size_t)(16*g + q*4 + r) * HIDq + colbase + 16*j + l15];
    __syncthreads();
    const int irow = tid >> 5, ic8 = (tid & 31) * 8;
    const int pcol = 256*(hf ^ 1) + ic8;
    int eprog_c = 0;   // cached min(e-progress) for our group; ~1 LLC load / ~28 steps

    for (int t = 0; t < Tt; ++t) {
      const int rb = t & 1, wb = rb ^ 1;
      u32* rslot = ring + (size_t)(t & (RS - 1)) * 32768;
      f32x4 a00 = {}, a01 = {}, a10 = {}, a11 = {};
#pragma unroll
      for (int kk = 0; kk < 16; ++kk) {
        f16x8 a = *(const f16x8*)&hL[rb][l15][kk*32 + q*8];
        if (kk & 1) {
          a01 = __builtin_amdgcn_mfma_f32_16x16x32_f16(a, Bf[0][kk], a01, 0, 0, 0);
          a11 = __builtin_amdgcn_mfma_f32_16x16x32_f16(a, Bf[1][kk], a11, 0, 0, 0);
        } else {
          a00 = __builtin_amdgcn_mfma_f32_16x16x32_f16(a, Bf[0][kk], a00, 0, 0, 0);
          a10 = __builtin_amdgcn_mfma_f32_16x16x32_f16(a, Bf[1][kk], a10, 0, 0, 0);
        }
      }
      const u32 tagw = (u32)(t + 1) << 16;
      u16 hbits[2][4];
#pragma unroll
      for (int j = 0; j < 2; ++j) {
        f32x4 s = j ? (a10 + a11) : (a00 + a01);
#pragma unroll
        for (int r = 0; r < 4; ++r) {
          float z = s[r] + dv[j][r];
          union { f16 h; u16 u; } cv; cv.h = (f16)fast_tanh(z);
          hbits[j][r] = cv.u;
          as32(&rslot[(size_t)(16*g + q*4 + r) * HIDq + colbase + 16*j + l15],
               tagw | (u32)cv.u);
        }
      }
#pragma unroll
      for (int j = 0; j < 2; ++j)
#pragma unroll
        for (int r = 0; r < 4; ++r) {
          union { u16 u; f16 h; } cv; cv.u = hbits[j][r];
          hL[wb][q*4 + r][colbase + 16*j + l15] = cv.h;
        }
      if (t < Tt - 1) {
#pragma unroll
        for (int j = 0; j < 2; ++j)
#pragma unroll
          for (int r = 0; r < 4; ++r)
            dv[j][r] = (float)d1[((size_t)(t+1)*64 + 16*g + q*4 + r) * HIDq + colbase + 16*j + l15];
      }
      // ring-slot gate for NEXT step's publish (slot (t+1)&31 holds h1_{t-31}; both
      // e-blocks of our group must have consumed it: eprog >= t-30). Ordered before the
      // next publish by the loop-end barrier. Cached: ~1 u64 LLC load per ~28 steps.
      if (tid == 0 && eprog_c < t - 30) {
        const u64* ep = (const u64*)&eprog[2 * g];
        for (;;) {
          u64 e2 = al64(ep);
          int lo = (int)(u32)e2, hi = (int)(u32)(e2 >> 32);
          eprog_c = lo < hi ? lo : hi;
          if (eprog_c >= t - 30) break;
          __builtin_amdgcn_s_sleep(1);
        }
      }
      // peer slab ingest (combined load + combined revalidation, s_sleep backoff)
      {
        const u64* pp = (const u64*)(rslot + (size_t)(16*g + irow) * HIDq) + (pcol >> 1);
        u64 v[4];
#pragma unroll
        for (int jj = 0; jj < 4; ++jj) v[jj] = al64(pp + jj);
        for (;;) {
          u32 bad = 0;
#pragma unroll
          for (int jj = 0; jj < 4; ++jj)
            bad |= ((u32)v[jj] ^ tagw) | ((u32)(v[jj] >> 32) ^ tagw);
          if ((bad & 0xFFFF0000u) == 0) break;
          __builtin_amdgcn_s_sleep(1);
#pragma unroll
          for (int jj = 0; jj < 4; ++jj) v[jj] = al64(pp + jj);
        }
        union { u32 wd[4]; f16x8 vv; } fr;
#pragma unroll
        for (int jj = 0; jj < 4; ++jj)
          fr.wd[jj] = __builtin_amdgcn_perm((u32)(v[jj] >> 32), (u32)v[jj], 0x05040100u);
        *(f16x8*)&hL[wb][irow][pcol] = fr.vv;
      }
      __syncthreads();
    }

  } else if (bb < 16) {
    // ================= e-block: d2_t = 0.05 d2 + 0.95 (h1_t @ W2^T + b2) -> d2r ==========
    const int eb = bb - 8, hf = eb & 1, g = eb >> 1;
    const int colbase = 256*hf + 32*w;
    f16x8 Bf[2][16];
#pragma unroll
    for (int j = 0; j < 2; ++j)
#pragma unroll
      for (int kk = 0; kk < 16; ++kk)
        Bf[j][kk] = *(const f16x8*)&W2[(size_t)(colbase + 16*j + l15) * HIDq + kk*32 + q*8];
    float bv[2] = { (float)b2[colbase + l15], (float)b2[colbase + 16 + l15] };
    float ed[2][4] = {};
    const int irow = tid >> 5, icol = (tid & 31) * 16;   // 16 rows x 32 thr x 16 u32-cols
    int sprog_c = 0;   // cached scan2 progress

    for (int t = 0; t < Tt; ++t) {
      if (tid == 0) {
        if (t > 0) as32(&eprog[eb], (u32)t);   // h1_{t-1} fully consumed (post-barrier)
        // d2-slot gate: about to overwrite d2_{t-32}; scan2 must have consumed it.
        if (sprog_c < t - 32) {
          for (;;) {
            sprog_c = (int)al32(&prog[eb]);
            if (sprog_c >= t - 32) break;
            __builtin_amdgcn_s_sleep(1);
          }
        }
      }
      const u32 tagw = (u32)(t + 1) << 16;
      // ingest h1_t (full 512 cols for our 16 rows): 8 u64/thread, combined revalidation
      {
        const u64* pp = (const u64*)(ring + (size_t)(t & (RS - 1)) * 32768
                          + (size_t)(16*g + irow) * HIDq) + (icol >> 1);
        u64 v[8];
#pragma unroll
        for (int jj = 0; jj < 8; ++jj) v[jj] = al64(pp + jj);
        for (;;) {
          u32 bad = 0;
#pragma unroll
          for (int jj = 0; jj < 8; ++jj)
            bad |= ((u32)v[jj] ^ tagw) | ((u32)(v[jj] >> 32) ^ tagw);
          if ((bad & 0xFFFF0000u) == 0) break;
          __builtin_amdgcn_s_sleep(1);
#pragma unroll
          for (int jj = 0; jj < 8; ++jj) v[jj] = al64(pp + jj);
        }
        union { u32 wd[8]; f16x8 vv[2]; } fr;
#pragma unroll
        for (int jj = 0; jj < 8; ++jj)
          fr.wd[jj] = __builtin_amdgcn_perm((u32)(v[jj] >> 32), (u32)v[jj], 0x05040100u);
        *(f16x8*)&hL[t & 1][irow][icol]     = fr.vv[0];
        *(f16x8*)&hL[t & 1][irow][icol + 8] = fr.vv[1];
      }
      __syncthreads();   // hL[t&1] complete; also orders publish after tid0's gates
      f32x4 a00 = {}, a01 = {}, a10 = {}, a11 = {};
#pragma unroll
      for (int kk = 0; kk < 16; ++kk) {
        f16x8 a = *(const f16x8*)&hL[t & 1][l15][kk*32 + q*8];
        if (kk & 1) {
          a01 = __builtin_amdgcn_mfma_f32_16x16x32_f16(a, Bf[0][kk], a01, 0, 0, 0);
          a11 = __builtin_amdgcn_mfma_f32_16x16x32_f16(a, Bf[1][kk], a11, 0, 0, 0);
        } else {
          a00 = __builtin_amdgcn_mfma_f32_16x16x32_f16(a, Bf[0][kk], a00, 0, 0, 0);
          a10 = __builtin_amdgcn_mfma_f32_16x16x32_f16(a, Bf[1][kk], a10, 0, 0, 0);
        }
      }
      u32* dslot = d2r + (size_t)(t & (DSd - 1)) * 32768;
#pragma unroll
      for (int j = 0; j < 2; ++j) {
        f32x4 s = j ? (a10 + a11) : (a00 + a01);
#pragma unroll
        for (int r = 0; r < 4; ++r) {
          ed[j][r] = 0.05f * ed[j][r] + 0.95f * (s[r] + bv[j]);
          union { f16 h; u16 u; } cv; cv.h = (f16)ed[j][r];
          as32(&dslot[(size_t)(16*g + q*4 + r) * HIDq + colbase + 16*j + l15],
               tagw | (u32)cv.u);
        }
      }
      // no 2nd barrier needed: next iter writes hL[(t+1)&1]; the single barrier keeps
      // waves <=1 step apart, so hL[t&1] can't be overwritten while still being read.
    }

  } else {
    // ================= scan2: h2_t = tanh(d2_t + h2_{t-1} @ Vh1^T) -> hb2 ===============
    const int sb = bb - 16, hf = sb & 1, g = sb >> 1;
    const int colbase = 256*hf + 32*w;
    f16x8 Bf[2][16];
#pragma unroll
    for (int j = 0; j < 2; ++j)
#pragma unroll
      for (int kk = 0; kk < 16; ++kk)
        Bf[j][kk] = *(const f16x8*)&Vh1[(size_t)(colbase + 16*j + l15) * HIDq + kk*32 + q*8];
    for (int i = tid; i < 1024; i += 512) {
      int r = i >> 6, c = (i & 63) * 8;
      f16x8 z = {};
      *(f16x8*)&hL[0][r][c] = z;
    }
    // d2_0 tagged poll (tag 1, slot 0) — long pipeline-fill wait, sleep in retry
    float dv[2][4];
    {
      const u32 tag2 = 1u << 16;
      const u32* dp = d2r + (size_t)(16*g + q*4) * HIDq + colbase + l15;
      u32 vv[8];
      for (;;) {
#pragma unroll
        for (int i = 0; i < 8; ++i) vv[i] = al32(dp + (size_t)(i & 3) * HIDq + 16*(i >> 2));
        u32 bad = 0;
#pragma unroll
        for (int i = 0; i < 8; ++i) bad |= vv[i] ^ tag2;
        if ((bad & 0xFFFF0000u) == 0) break;
        __builtin_amdgcn_s_sleep(1);
      }
#pragma unroll
      for (int j = 0; j < 2; ++j)
#pragma unroll
        for (int r = 0; r < 4; ++r) {
          union { u16 u; f16 h; } cv; cv.u = (u16)vv[j*4 + r];
          dv[j][r] = (float)cv.h;
        }
    }
    __syncthreads();
    const int irow = tid >> 5, ic8 = (tid & 31) * 8;
    const int pcol = 256*(hf ^ 1) + ic8;

    for (int t = 0; t < Tt; ++t) {
      const int rb = t & 1, wb = rb ^ 1, slot = t & 1;
      if (tid == 0 && t > 0) as32(&prog[sb], (u32)t);   // d2_t consumed last iter (post-barrier)
      f32x4 a00 = {}, a01 = {}, a10 = {}, a11 = {};
#pragma unroll
      for (int kk = 0; kk < 16; ++kk) {
        f16x8 a = *(const f16x8*)&hL[rb][l15][kk*32 + q*8];
        if (kk & 1) {
          a01 = __builtin_amdgcn_mfma_f32_16x16x32_f16(a, Bf[0][kk], a01, 0, 0, 0);
          a11 = __builtin_amdgcn_mfma_f32_16x16x32_f16(a, Bf[1][kk], a11, 0, 0, 0);
        } else {
          a00 = __builtin_amdgcn_mfma_f32_16x16x32_f16(a, Bf[0][kk], a00, 0, 0, 0);
          a10 = __builtin_amdgcn_mfma_f32_16x16x32_f16(a, Bf[1][kk], a10, 0, 0, 0);
        }
      }
      const u32 tagw = (u32)(t + 1) << 16;
      u16 hbits[2][4];
#pragma unroll
      for (int j = 0; j < 2; ++j) {
        f32x4 s = j ? (a10 + a11) : (a00 + a01);
#pragma unroll
        for (int r = 0; r < 4; ++r) {
          float z = s[r] + dv[j][r];
          union { f16 h; u16 u; } cv; cv.h = (f16)fast_tanh(z);
          hbits[j][r] = cv.u;
          as32(&hb2[(size_t)(slot*64 + 16*g + q*4 + r) * HIDq + colbase + 16*j + l15],
               tagw | (u32)cv.u);
        }
      }
#pragma unroll
      for (int j = 0; j < 2; ++j)
#pragma unroll
        for (int r = 0; r < 4; ++r) {
          union { u16 u; f16 h; } cv; cv.u = hbits[j][r];
          hL[wb][q*4 + r][colbase + 16*j + l15] = cv.h;
        }

      // MERGED wait: d2_{t+1} poll + hb2 peer-slab ingest in ONE combined revalidation
      {
        const bool have_d = (t < Tt - 1);
        const u32 tag2 = (u32)(t + 2) << 16;
        const u32* dp = d2r + (size_t)((t + 1) & (DSd - 1)) * 32768
                      + (size_t)(16*g + q*4) * HIDq + colbase + l15;
        const u64* pp = (const u64*)&hb2[(size_t)(slot*64 + 16*g + irow) * HIDq] + (pcol >> 1);
        u32 vv[8];
        u64 v[4];
        if (have_d) {
#pragma unroll
          for (int i = 0; i < 8; ++i) vv[i] = al32(dp + (size_t)(i & 3) * HIDq + 16*(i >> 2));
        }
#pragma unroll
        for (int jj = 0; jj < 4; ++jj) v[jj] = al64(pp + jj);
        for (;;) {
          u32 badp = 0;
#pragma unroll
          for (int jj = 0; jj < 4; ++jj)
            badp |= ((u32)v[jj] ^ tagw) | ((u32)(v[jj] >> 32) ^ tagw);
          badp &= 0xFFFF0000u;
          u32 badd = 0;
          if (have_d) {
#pragma unroll
            for (int i = 0; i < 8; ++i) badd |= vv[i] ^ tag2;
            badd &= 0xFFFF0000u;
          }
          if (!(badp | badd)) break;
          __builtin_amdgcn_s_sleep(1);
          if (badp) {
#pragma unroll
            for (int jj = 0; jj < 4; ++jj) v[jj] = al64(pp + jj);
          }
          if (badd) {
#pragma unroll
            for (int i = 0; i < 8; ++i) vv[i] = al32(dp + (size_t)(i & 3) * HIDq + 16*(i >> 2));
          }
        }
        if (have_d) {
#pragma unroll
          for (int j = 0; j < 2; ++j)
#pragma unroll
            for (int r = 0; r < 4; ++r) {
              union { u16 u; f16 h; } cv; cv.u = (u16)vv[j*4 + r];
              dv[j][r] = (float)cv.h;
            }
        }
        union { u32 wd[4]; f16x8 vr; } fr;
#pragma unroll
        for (int jj = 0; jj < 4; ++jj)
          fr.wd[jj] = __builtin_amdgcn_perm((u32)(v[jj] >> 32), (u32)v[jj], 0x05040100u);
        *(f16x8*)&hL[wb][irow][pcol] = fr.vr;
      }
      __syncthreads();   // hL[wb] complete for step t+1
    }
  }
}

// ---- final: out[64,128] = h_last[64,512] @ fc_w^T + fc_b; h from tagged buffer ----
__global__ __launch_bounds__(64) void k_final(const u32* __restrict__ h, const f16* __restrict__ fw,
                                              const f16* __restrict__ fb, void* __restrict__ outv,
                                              const int* __restrict__ dmode) {
  __shared__ f16 hA[16][520];
  __shared__ f16 Bw[16][520];
  const int mb = blockIdx.x & 3, nb = blockIdx.x >> 2;
  const int lane = threadIdx.x, l15 = lane & 15, q = lane >> 4;
  for (int i = lane; i < 16 * 128; i += 64) {   // tagged u32 -> f16 (low 16)
    int r = i >> 7, c = (i & 127) * 4;
    const u64* p = (const u64*)&h[(size_t)(mb*16 + r) * 512 + c];
    u64 v0 = al64(p), v1 = al64(p + 1);
    *(u32*)&hA[r][c]     = __builtin_amdgcn_perm((u32)(v0 >> 32), (u32)v0, 0x05040100u);
    *(u32*)&hA[r][c + 2] = __builtin_amdgcn_perm((u32)(v1 >> 32), (u32)v1, 0x05040100u);
  }
  for (int i = lane; i < 16 * 64; i += 64) {
    int r = i >> 6, c = (i & 63) * 8;
    *(f16x8*)&Bw[r][c] = *(const f16x8*)&fw[(size_t)(nb*16 + r) * 512 + c];
  }
  __syncthreads();
  f32x4 acc = {};
#pragma unroll
  for (int kk = 0; kk < 16; ++kk) {
    f16x8 a = *(const f16x8*)&hA[l15][kk*32 + q*8];
    f16x8 b = *(const f16x8*)&Bw[l15][kk*32 + q*8];
    acc = __builtin_amdgcn_mfma_f32_16x16x32_f16(a, b, acc, 0, 0, 0);
  }
  float bv = (float)fb[nb*16 + l15];
  int md = *dmode;
#pragma unroll
  for (int r = 0; r < 4; ++r) {
    int idx = (mb*16 + q*4 + r) * 128 + nb*16 + l15;
    float val = acc[r] + bv;
    if (md) ((float*)outv)[idx] = val;
    else    ((u16*)outv)[idx]   = f2bf(val);
  }
}

extern "C" void kernel_launch(void* const* d_in, const int* in_sizes, int n_in,
                              void* d_out, int out_size, void* d_ws, size_t ws_size,
                              hipStream_t stream) {
  if (ws_size < 88080384ull) {
    k_zero<<<32, 256, 0, stream>>>((u16*)d_out);
    return;
  }
  char* ws = (char*)d_ws;
  // ---- control / tagged buffers ----
  u32* hb2   = (u32*)(ws + 0);           // h2 tagged, 2 slots: 256 KiB
  u32* prog  = (u32*)(ws + 262144);      // 8 u32 scan2 progress
  u32* eprog = (u32*)(ws + 262176);      // 8 u32 e-block progress
  int* dmode = (int*)(ws + 262208);
  // ---- weights (f16) ----
  f16* Wx0f = (f16*)(ws + 262656);       // 131072 B
  f16* Uc0f = (f16*)(ws + 393728);       // 262144
  f16* Vh0f = (f16*)(ws + 655872);       // 524288
  f16* Wx1f = (f16*)(ws + 1180160);      // 262144
  f16* Uc1f = (f16*)(ws + 1442304);      // 262144
  f16* Vh1f = (f16*)(ws + 1704448);      // 524288
  f16* fcwf = (f16*)(ws + 2228736);      // 131072
  f16* bx0f = (f16*)(ws + 2359808);      // 512
  f16* bx1f = (f16*)(ws + 2360320);      // 512
  f16* fcbf = (f16*)(ws + 2360832);      // 256
  f16* Wx1T = (f16*)(ws + 2361344);      // 262144  (Wx1 transposed [512][256])
  f16* W2f  = (f16*)(ws + 2623488);      // 524288  (Uc1 @ Wx1, [512][512])
  f16* b2f  = (f16*)(ws + 3147776);      // 1024    (Uc1 @ bx1)
  // ---- big buffers (with lifetime overlays) ----
  f16* x16  = (f16*)(ws + 4194304);      // 16 MiB, dead after xp1-gemm
  u32* ring = (u32*)(ws + 4194304);      // 4 MiB: h1 ring (32 slots), overlays x16
  f16* xp1  = (f16*)(ws + 20971520);     // 16 MiB, dead after ema
  f16* cb1  = (f16*)(ws + 37748736);     // 16 MiB, dead after d1-gemm
  u32* d2r  = (u32*)(ws + 37748736);     // 4 MiB: d2 ring (32 slots), overlays cb1
  f16* d1   = (f16*)(ws + 54525952);     // 32 MiB, time-major [t][64][512], persists

  k_probe<<<1, 256, 0, stream>>>((const u16*)d_in[1], dmode);
  auto cvt = [&](const void* s, f16* d, int n) {
    int n8 = n / 8;
    k_cvt<<<dim3((n8 + 255) / 256), dim3(256), 0, stream>>>(s, d, n8, dmode);
  };
  cvt(d_in[0],  x16,  8388608);
  cvt(d_in[1],  Wx0f, 65536);
  cvt(d_in[2],  bx0f, 256);
  cvt(d_in[3],  Uc0f, 131072);
  cvt(d_in[4],  Vh0f, 262144);
  cvt(d_in[5],  Wx1f, 131072);
  cvt(d_in[6],  bx1f, 256);
  cvt(d_in[7],  Uc1f, 131072);
  cvt(d_in[8],  Vh1f, 262144);
  cvt(d_in[9],  fcwf, 65536);
  cvt(d_in[10], fcbf, 128);

  // layer-2 weight merge: W2 = Uc1 @ Wx1, b2 = Uc1 @ bx1
  k_tr<<<512, 256, 0, stream>>>(Wx1f, Wx1T, 256, 9);
  k_bias<<<1, 512, 0, stream>>>(Uc1f, bx1f, b2f);
  k_gemm<false, false><<<dim3(4, 4), 256, 0, stream>>>(Uc1f, Wx1T, nullptr, W2f, 512, 512, 256);

  // layer-1 front (unchanged proven path): xp1 -> EMA -> d1 (time-major)
  k_gemm<true , false><<<dim3(2, 256), 256, 0, stream>>>(x16, Wx0f, bx0f, xp1, 32768, 256, 256);
  k_ema<<<512, 128, 0, stream>>>(xp1, cb1);
  hipMemsetAsync(ws + 4194304, 0, 4194304, stream);             // h1 ring (x16 now dead)
  k_gemm<false, true ><<<dim3(4, 256), 256, 0, stream>>>(cb1, Uc0f, nullptr, d1, 32768, 512, 256);
  hipMemsetAsync(ws + 37748736, 0, 4194304, stream);            // d2 ring (cb1 now dead)
  hipMemsetAsync(ws, 0, 262208, stream);                        // hb2 + prog + eprog

  // fused pipeline: scan1 || e-GEMM/EMA || scan2
  k_mega<<<24, 512, 0, stream>>>(Vh0f, Vh1f, W2f, b2f, d1, ring, d2r, hb2, prog, eprog);

  // head: h2_511 (slot 1) in hb2 (tagged)
  k_final<<<32, 64, 0, stream>>>(hb2 + 64 * 512, fcwf, fcbf, d_out, dmode);
}